// Round 3
// baseline (612.255 us; speedup 1.0000x reference)
//
#include <hip/hip_runtime.h>
#include <cstdint>
#include <cstddef>

#define BB 16
#define NN 8192
#define DD 384
#define HH 128
#define KK 8
#define DEG 16

typedef short bf8_t __attribute__((ext_vector_type(8)));
typedef float f4_t __attribute__((ext_vector_type(4)));

__device__ __forceinline__ unsigned short f2bf(float f) {
  unsigned int u = __float_as_uint(f);
  u += 0x7FFFu + ((u >> 16) & 1u);   // RNE
  return (unsigned short)(u >> 16);
}

__device__ __forceinline__ bf8_t pack8(float4 f0, float4 f1) {
  union { unsigned short us[8]; bf8_t v; } pk;
  pk.us[0] = f2bf(f0.x); pk.us[1] = f2bf(f0.y);
  pk.us[2] = f2bf(f0.z); pk.us[3] = f2bf(f0.w);
  pk.us[4] = f2bf(f1.x); pk.us[5] = f2bf(f1.y);
  pk.us[6] = f2bf(f1.z); pk.us[7] = f2bf(f1.w);
  return pk.v;
}

// ---------------------------------------------------------------------------
// Kprep: (a) fold q@W[384:,:]+bias into per-batch base vectors;
// (b) transpose+convert W1[:384]/P1[:384] to bf16 [H][D]; (c) zero normsq.
// ---------------------------------------------------------------------------
__global__ __launch_bounds__(256) void kprep(
    const float* __restrict__ q, const float* __restrict__ W1,
    const float* __restrict__ b1, const float* __restrict__ P1,
    const float* __restrict__ pb1,
    unsigned short* __restrict__ W1t, unsigned short* __restrict__ P1t,
    float* __restrict__ base1, float* __restrict__ baseP,
    float* __restrict__ normsq)
{
  int blk = blockIdx.x, t = threadIdx.x;
  if (blk < 32) {
    int b = blk >> 1, net = blk & 1;
    const float* W = (net ? P1 : W1) + (size_t)DD * HH;   // q-half rows
    const float* qb = q + b * DD;
    int h = t & 127, half = t >> 7;
    int d0 = half * 192;
    float a0 = 0.f, a1 = 0.f, a2 = 0.f, a3 = 0.f;
    for (int d = d0; d < d0 + 192; d += 4) {
      a0 = fmaf(qb[d],     W[(size_t)d * HH + h],       a0);
      a1 = fmaf(qb[d + 1], W[(size_t)(d + 1) * HH + h], a1);
      a2 = fmaf(qb[d + 2], W[(size_t)(d + 2) * HH + h], a2);
      a3 = fmaf(qb[d + 3], W[(size_t)(d + 3) * HH + h], a3);
    }
    __shared__ float red[256];
    red[t] = (a0 + a1) + (a2 + a3);
    __syncthreads();
    if (t < 128) {
      float tot = red[t] + red[t + 128] + (net ? pb1[h] : b1[h]);
      (net ? baseP : base1)[b * HH + h] = tot;
    }
  } else {
    int e = (blk - 32) * 3072 + t;   // 32 blocks x 3072 = 2*49152 elems
    for (int it = 0; it < 12; ++it, e += 256) {
      int net = e / 49152;
      int r = e - net * 49152;
      int d = r >> 7;
      int h = r & 127;
      float v = (net ? P1 : W1)[d * HH + h];
      (net ? P1t : W1t)[h * DD + d] = f2bf(v);
    }
    if (blk == 32 && t < BB) normsq[t] = 0.f;
  }
}

// ---------------------------------------------------------------------------
// Kgemm: one net per block. Full per-net B (128x384 bf16, 96 KB) resident in
// LDS, XOR-swizzled (part p of row h at p^(h&7)) -> conflict-free b128 reads.
// ONE barrier total; K-loop has zero barriers so the depth-2 A register
// prefetch is truly async. 512 thr / 8 waves, M=32/wave (B-frags reused
// across 2 row groups). Net-pair blocks 8 apart -> same XCD under round-robin
// (L2/L3 reuse of emb rows).
// ---------------------------------------------------------------------------
__global__ __launch_bounds__(512, 2) void kgemm(
    const float* __restrict__ emb,
    const unsigned short* __restrict__ W1t, const unsigned short* __restrict__ P1t,
    const float* __restrict__ base1, const float* __restrict__ baseP,
    const float* __restrict__ W2, const float* __restrict__ b2,
    const float* __restrict__ P2, const float* __restrict__ pb2,
    float* __restrict__ rawamps, float* __restrict__ pslogit)
{
  __shared__ __align__(16) unsigned short sB[128 * 384];   // 96 KB
  __shared__ float sW2a[128 * 9];
  __shared__ float sBase[128];
  __shared__ float sP2[128];
  __shared__ float sB2[8];

  const int g = blockIdx.x;
  const int slot = g & 7;
  const int net = (g >> 3) & 1;
  const int wid = (g >> 4) * 8 + slot;       // 0..511
  const int b = wid >> 5;
  const int rowbase = (wid & 31) * 256;

  const int t = threadIdx.x;
  const int w = t >> 6, lane = t & 63, q = lane >> 4, ln = lane & 15;

  // ---- B prologue ----
  const unsigned short* Wt = net ? P1t : W1t;
  {
    int h = t >> 2, p0 = t & 3;
#pragma unroll
    for (int i = 0; i < 12; ++i) {
      int p = p0 + i * 4;
      uint4 v = *(const uint4*)(Wt + h * DD + p * 8);
      *(uint4*)((char*)sB + h * 768 + ((p ^ (h & 7)) << 4)) = v;
    }
  }
  if (t < 128) sBase[t] = (net ? baseP : base1)[b * HH + t];
  if (net == 0) {
    for (int e = t; e < HH * KK; e += 512) {
      int h = e >> 3, kk = e & 7;
      sW2a[h * 9 + kk] = W2[e];
    }
    if (t < 8) sB2[t] = b2[t];
  } else if (t >= 128 && t < 256) {
    sP2[t - 128] = P2[t - 128];
  }

  // ---- A depth-2 prefetch ----
  const float* ar0 = emb + (size_t)(b * NN + rowbase + w * 32 + ln) * DD + q * 8;
  const float* ar1 = ar0 + (size_t)16 * DD;
  float4 pf[2][4];
  pf[0][0] = ((const float4*)ar0)[0];        pf[0][1] = ((const float4*)ar0)[1];
  pf[0][2] = ((const float4*)ar1)[0];        pf[0][3] = ((const float4*)ar1)[1];
  pf[1][0] = ((const float4*)(ar0 + 32))[0]; pf[1][1] = ((const float4*)(ar0 + 32))[1];
  pf[1][2] = ((const float4*)(ar1 + 32))[0]; pf[1][3] = ((const float4*)(ar1 + 32))[1];

  f4_t acc[2][8];
  f4_t zero = {0.f, 0.f, 0.f, 0.f};
#pragma unroll
  for (int i = 0; i < 8; ++i) { acc[0][i] = zero; acc[1][i] = zero; }

  __syncthreads();                           // the ONLY barrier

#pragma unroll
  for (int j = 0; j < 12; ++j) {
    const int s = j & 1;
    bf8_t af0 = pack8(pf[s][0], pf[s][1]);
    bf8_t af1 = pack8(pf[s][2], pf[s][3]);
    if (j + 2 < 12) {
      const float* p0 = ar0 + (j + 2) * 32;
      const float* p1 = ar1 + (j + 2) * 32;
      pf[s][0] = ((const float4*)p0)[0]; pf[s][1] = ((const float4*)p0)[1];
      pf[s][2] = ((const float4*)p1)[0]; pf[s][3] = ((const float4*)p1)[1];
    }
    const int jb = j * 4;                    // 16B-part group base
#pragma unroll
    for (int ct = 0; ct < 8; ++ct) {
      const int h = ct * 16 + ln;
      bf8_t bf = *(const bf8_t*)((const char*)sB + h * 768 + (((jb + q) ^ (ln & 7)) << 4));
      acc[0][ct] = __builtin_amdgcn_mfma_f32_16x16x32_bf16(af0, bf, acc[0][ct], 0, 0, 0);
      acc[1][ct] = __builtin_amdgcn_mfma_f32_16x16x32_bf16(af1, bf, acc[1][ct], 0, 0, 0);
    }
  }

  // ---- epilogue: relu + second matmul + shuffle-reduce over 16 lanes ----
  const float pb2v = pb2[0];
#pragma unroll
  for (int grp = 0; grp < 2; ++grp) {
#pragma unroll
    for (int r = 0; r < 4; ++r) {
      const int grow = rowbase + w * 32 + grp * 16 + q * 4 + r;
      if (net == 0) {
        float s[8];
#pragma unroll
        for (int kk = 0; kk < 8; ++kk) s[kk] = 0.f;
#pragma unroll
        for (int ct = 0; ct < 8; ++ct) {
          int col = ct * 16 + ln;
          float h1 = fmaxf(acc[grp][ct][r] + sBase[col], 0.f);
#pragma unroll
          for (int kk = 0; kk < 8; ++kk) s[kk] = fmaf(h1, sW2a[col * 9 + kk], s[kk]);
        }
#pragma unroll
        for (int off = 1; off < 16; off <<= 1)
#pragma unroll
          for (int kk = 0; kk < 8; ++kk) s[kk] += __shfl_xor(s[kk], off, 64);
        if (ln == 0) {
          float4 o0, o1;
          o0.x = s[0] + sB2[0]; o0.y = s[1] + sB2[1];
          o0.z = s[2] + sB2[2]; o0.w = s[3] + sB2[3];
          o1.x = s[4] + sB2[4]; o1.y = s[5] + sB2[5];
          o1.z = s[6] + sB2[6]; o1.w = s[7] + sB2[7];
          float4* dst = (float4*)(rawamps + (size_t)(b * NN + grow) * KK);
          dst[0] = o0; dst[1] = o1;
        }
      } else {
        float ps = 0.f;
#pragma unroll
        for (int ct = 0; ct < 8; ++ct) {
          int col = ct * 16 + ln;
          float hp = fmaxf(acc[grp][ct][r] + sBase[col], 0.f);
          ps = fmaf(hp, sP2[col], ps);
        }
#pragma unroll
        for (int off = 1; off < 16; off <<= 1) ps += __shfl_xor(ps, off, 64);
        if (ln == 0) pslogit[b * NN + grow] = ps + pb2v;
      }
    }
  }
}

// ---------------------------------------------------------------------------
// applyscale: amps = raw * (1 + sigmoid(pslogit) + label)
// ---------------------------------------------------------------------------
__global__ __launch_bounds__(256) void applyscale(
    const float* __restrict__ raw, const float* __restrict__ psl,
    const int* __restrict__ lab, float* __restrict__ amps)
{
  int node = blockIdx.x * 256 + threadIdx.x;   // 131072
  float sc = 1.f + 1.f / (1.f + __expf(-psl[node])) + (float)lab[node];
  const float4* r = (const float4*)(raw + (size_t)node * KK);
  float4 v0 = r[0], v1 = r[1];
  v0.x *= sc; v0.y *= sc; v0.z *= sc; v0.w *= sc;
  v1.x *= sc; v1.y *= sc; v1.z *= sc; v1.w *= sc;
  float4* d = (float4*)(amps + (size_t)node * KK);
  d[0] = v0; d[1] = v1;
}

// ---------------------------------------------------------------------------
// Diffusion: 8 threads per node (one per k). Gather loads are 32B-contiguous
// per 8-lane group; 32 waves/CU occupancy hides scattered-load latency.
// Per-step norms cancel; only final norm needed.
// ---------------------------------------------------------------------------
template<bool MUL, bool NRM>
__global__ __launch_bounds__(256) void sg8(
    const int* __restrict__ nbr, const float* __restrict__ src,
    const float* __restrict__ mult, float* __restrict__ out,
    float* __restrict__ normsq)
{
  int idx = blockIdx.x * 256 + threadIdx.x;    // 0..1048575
  int node = idx >> 3, k = idx & 7;
  int base = node & ~(NN - 1);
  const int4* nbp = (const int4*)(nbr + (size_t)node * DEG);
  int4 n0 = nbp[0], n1 = nbp[1], n2 = nbp[2], n3 = nbp[3];
  float a = 0.f;
  a += src[(size_t)(base + n0.x) * KK + k];
  a += src[(size_t)(base + n0.y) * KK + k];
  a += src[(size_t)(base + n0.z) * KK + k];
  a += src[(size_t)(base + n0.w) * KK + k];
  a += src[(size_t)(base + n1.x) * KK + k];
  a += src[(size_t)(base + n1.y) * KK + k];
  a += src[(size_t)(base + n1.z) * KK + k];
  a += src[(size_t)(base + n1.w) * KK + k];
  a += src[(size_t)(base + n2.x) * KK + k];
  a += src[(size_t)(base + n2.y) * KK + k];
  a += src[(size_t)(base + n2.z) * KK + k];
  a += src[(size_t)(base + n2.w) * KK + k];
  a += src[(size_t)(base + n3.x) * KK + k];
  a += src[(size_t)(base + n3.y) * KK + k];
  a += src[(size_t)(base + n3.z) * KK + k];
  a += src[(size_t)(base + n3.w) * KK + k];
  if (MUL) a *= mult[(size_t)node * KK + k];
  out[(size_t)node * KK + k] = a;
  if (NRM) {
    float ss = a * a;
#pragma unroll
    for (int o = 1; o < 64; o <<= 1) ss += __shfl_xor(ss, o, 64);
    if ((threadIdx.x & 63) == 0) atomicAdd(&normsq[node >> 13], ss);
  }
}

__global__ __launch_bounds__(256) void fout(
    const float* __restrict__ u, const float* __restrict__ normsq,
    float* __restrict__ out)
{
  int idx = blockIdx.x * 256 + threadIdx.x;
  float ns = normsq[idx >> 13];
  float inv = ns > 0.f ? rsqrtf(ns) : 1.f;
  const float4* p = (const float4*)(u + (size_t)idx * KK);
  float4 v0 = p[0], v1 = p[1];
  out[idx] = (fabsf(v0.x) + fabsf(v0.y) + fabsf(v0.z) + fabsf(v0.w) +
              fabsf(v1.x) + fabsf(v1.y) + fabsf(v1.z) + fabsf(v1.w)) * inv;
}

extern "C" void kernel_launch(void* const* d_in, const int* in_sizes, int n_in,
                              void* d_out, int out_size, void* d_ws, size_t ws_size,
                              hipStream_t stream) {
  const float* q   = (const float*)d_in[0];
  const float* emb = (const float*)d_in[1];
  const int*   nbr = (const int*)d_in[2];
  const int*   lab = (const int*)d_in[3];
  const float* W1  = (const float*)d_in[4];
  const float* b1  = (const float*)d_in[5];
  const float* W2  = (const float*)d_in[6];
  const float* b2  = (const float*)d_in[7];
  const float* P1  = (const float*)d_in[8];
  const float* pb1 = (const float*)d_in[9];
  const float* P2  = (const float*)d_in[10];
  const float* pb2 = (const float*)d_in[11];
  float* out = (float*)d_out;

  const size_t NK = (size_t)BB * NN * KK;     // 1,048,576 floats
  float* ws     = (float*)d_ws;
  float* buf0   = ws;                         // raw amps, later u2m
  float* buf1   = buf0 + NK;                  // scaled amps, later u3
  float* buf2   = buf1 + NK;                  // u1m
  float* psl    = buf2 + NK;                  // 131072
  float* base1  = psl + (size_t)BB * NN;
  float* baseP  = base1 + BB * HH;
  float* normsq = baseP + BB * HH;
  unsigned short* W1t = (unsigned short*)(normsq + 16);
  unsigned short* P1t = W1t + (size_t)HH * DD;

  kprep<<<64, 256, 0, stream>>>(q, W1, b1, P1, pb1, W1t, P1t, base1, baseP, normsq);
  kgemm<<<1024, 512, 0, stream>>>(emb, W1t, P1t, base1, baseP, W2, b2, P2, pb2,
                                  buf0, psl);
  applyscale<<<512, 256, 0, stream>>>(buf0, psl, lab, buf1);
  sg8<true, false><<<4096, 256, 0, stream>>>(nbr, buf1, buf1, buf2, normsq);  // u1m
  sg8<true, false><<<4096, 256, 0, stream>>>(nbr, buf2, buf1, buf0, normsq);  // u2m
  sg8<false, true><<<4096, 256, 0, stream>>>(nbr, buf0, buf0, buf1, normsq);  // u3
  fout<<<512, 256, 0, stream>>>(buf1, normsq, out);
}

// Round 4
// 423.250 us; speedup vs baseline: 1.4466x; 1.4466x over previous
//
#include <hip/hip_runtime.h>
#include <cstdint>
#include <cstddef>

#define BB 16
#define NN 8192
#define DD 384
#define HH 128
#define KK 8
#define DEG 16

typedef short bf8_t __attribute__((ext_vector_type(8)));
typedef float f4_t __attribute__((ext_vector_type(4)));

__device__ __forceinline__ unsigned short f2bf(float f) {
  unsigned int u = __float_as_uint(f);
  u += 0x7FFFu + ((u >> 16) & 1u);   // RNE
  return (unsigned short)(u >> 16);
}

__device__ __forceinline__ bf8_t pack8(float4 f0, float4 f1) {
  union { unsigned short us[8]; bf8_t v; } pk;
  pk.us[0] = f2bf(f0.x); pk.us[1] = f2bf(f0.y);
  pk.us[2] = f2bf(f0.z); pk.us[3] = f2bf(f0.w);
  pk.us[4] = f2bf(f1.x); pk.us[5] = f2bf(f1.y);
  pk.us[6] = f2bf(f1.z); pk.us[7] = f2bf(f1.w);
  return pk.v;
}

// ---------------------------------------------------------------------------
// Kprep: (a) fold q@W[384:,:]+bias into per-batch base vectors;
// (b) transpose+convert W1[:384]/P1[:384] to bf16 [H][D]; (c) zero normsq.
// ---------------------------------------------------------------------------
__global__ __launch_bounds__(256) void kprep(
    const float* __restrict__ q, const float* __restrict__ W1,
    const float* __restrict__ b1, const float* __restrict__ P1,
    const float* __restrict__ pb1,
    unsigned short* __restrict__ W1t, unsigned short* __restrict__ P1t,
    float* __restrict__ base1, float* __restrict__ baseP,
    float* __restrict__ normsq)
{
  int blk = blockIdx.x, t = threadIdx.x;
  if (blk < 32) {
    int b = blk >> 1, net = blk & 1;
    const float* W = (net ? P1 : W1) + (size_t)DD * HH;   // q-half rows
    const float* qb = q + b * DD;
    int h = t & 127, half = t >> 7;
    int d0 = half * 192;
    float a0 = 0.f, a1 = 0.f, a2 = 0.f, a3 = 0.f;
    for (int d = d0; d < d0 + 192; d += 4) {
      a0 = fmaf(qb[d],     W[(size_t)d * HH + h],       a0);
      a1 = fmaf(qb[d + 1], W[(size_t)(d + 1) * HH + h], a1);
      a2 = fmaf(qb[d + 2], W[(size_t)(d + 2) * HH + h], a2);
      a3 = fmaf(qb[d + 3], W[(size_t)(d + 3) * HH + h], a3);
    }
    __shared__ float red[256];
    red[t] = (a0 + a1) + (a2 + a3);
    __syncthreads();
    if (t < 128) {
      float tot = red[t] + red[t + 128] + (net ? pb1[h] : b1[h]);
      (net ? baseP : base1)[b * HH + h] = tot;
    }
  } else {
    int e = (blk - 32) * 3072 + t;   // 32 blocks x 3072 = 2*49152 elems
    for (int it = 0; it < 12; ++it, e += 256) {
      int net = e / 49152;
      int r = e - net * 49152;
      int d = r >> 7;
      int h = r & 127;
      float v = (net ? P1 : W1)[d * HH + h];
      (net ? P1t : W1t)[h * DD + d] = f2bf(v);
    }
    if (blk == 32 && t < BB) normsq[t] = 0.f;
  }
}

// ---------------------------------------------------------------------------
// Kgemm: one net per block. Full per-net B (128x384 bf16, 96 KB) resident in
// LDS, XOR-swizzled; ONE barrier total; depth-2 A register prefetch.
// (unchanged from round 3 — it fell out of the top-5, i.e. it worked)
// ---------------------------------------------------------------------------
__global__ __launch_bounds__(512, 2) void kgemm(
    const float* __restrict__ emb,
    const unsigned short* __restrict__ W1t, const unsigned short* __restrict__ P1t,
    const float* __restrict__ base1, const float* __restrict__ baseP,
    const float* __restrict__ W2, const float* __restrict__ b2,
    const float* __restrict__ P2, const float* __restrict__ pb2,
    float* __restrict__ rawamps, float* __restrict__ pslogit)
{
  __shared__ __align__(16) unsigned short sB[128 * 384];   // 96 KB
  __shared__ float sW2a[128 * 9];
  __shared__ float sBase[128];
  __shared__ float sP2[128];
  __shared__ float sB2[8];

  const int g = blockIdx.x;
  const int slot = g & 7;
  const int net = (g >> 3) & 1;
  const int wid = (g >> 4) * 8 + slot;       // 0..511
  const int b = wid >> 5;
  const int rowbase = (wid & 31) * 256;

  const int t = threadIdx.x;
  const int w = t >> 6, lane = t & 63, q = lane >> 4, ln = lane & 15;

  const unsigned short* Wt = net ? P1t : W1t;
  {
    int h = t >> 2, p0 = t & 3;
#pragma unroll
    for (int i = 0; i < 12; ++i) {
      int p = p0 + i * 4;
      uint4 v = *(const uint4*)(Wt + h * DD + p * 8);
      *(uint4*)((char*)sB + h * 768 + ((p ^ (h & 7)) << 4)) = v;
    }
  }
  if (t < 128) sBase[t] = (net ? baseP : base1)[b * HH + t];
  if (net == 0) {
    for (int e = t; e < HH * KK; e += 512) {
      int h = e >> 3, kk = e & 7;
      sW2a[h * 9 + kk] = W2[e];
    }
    if (t < 8) sB2[t] = b2[t];
  } else if (t >= 128 && t < 256) {
    sP2[t - 128] = P2[t - 128];
  }

  const float* ar0 = emb + (size_t)(b * NN + rowbase + w * 32 + ln) * DD + q * 8;
  const float* ar1 = ar0 + (size_t)16 * DD;
  float4 pf[2][4];
  pf[0][0] = ((const float4*)ar0)[0];        pf[0][1] = ((const float4*)ar0)[1];
  pf[0][2] = ((const float4*)ar1)[0];        pf[0][3] = ((const float4*)ar1)[1];
  pf[1][0] = ((const float4*)(ar0 + 32))[0]; pf[1][1] = ((const float4*)(ar0 + 32))[1];
  pf[1][2] = ((const float4*)(ar1 + 32))[0]; pf[1][3] = ((const float4*)(ar1 + 32))[1];

  f4_t acc[2][8];
  f4_t zero = {0.f, 0.f, 0.f, 0.f};
#pragma unroll
  for (int i = 0; i < 8; ++i) { acc[0][i] = zero; acc[1][i] = zero; }

  __syncthreads();                           // the ONLY barrier

#pragma unroll
  for (int j = 0; j < 12; ++j) {
    const int s = j & 1;
    bf8_t af0 = pack8(pf[s][0], pf[s][1]);
    bf8_t af1 = pack8(pf[s][2], pf[s][3]);
    if (j + 2 < 12) {
      const float* p0 = ar0 + (j + 2) * 32;
      const float* p1 = ar1 + (j + 2) * 32;
      pf[s][0] = ((const float4*)p0)[0]; pf[s][1] = ((const float4*)p0)[1];
      pf[s][2] = ((const float4*)p1)[0]; pf[s][3] = ((const float4*)p1)[1];
    }
    const int jb = j * 4;
#pragma unroll
    for (int ct = 0; ct < 8; ++ct) {
      const int h = ct * 16 + ln;
      bf8_t bf = *(const bf8_t*)((const char*)sB + h * 768 + (((jb + q) ^ (ln & 7)) << 4));
      acc[0][ct] = __builtin_amdgcn_mfma_f32_16x16x32_bf16(af0, bf, acc[0][ct], 0, 0, 0);
      acc[1][ct] = __builtin_amdgcn_mfma_f32_16x16x32_bf16(af1, bf, acc[1][ct], 0, 0, 0);
    }
  }

  const float pb2v = pb2[0];
#pragma unroll
  for (int grp = 0; grp < 2; ++grp) {
#pragma unroll
    for (int r = 0; r < 4; ++r) {
      const int grow = rowbase + w * 32 + grp * 16 + q * 4 + r;
      if (net == 0) {
        float s[8];
#pragma unroll
        for (int kk = 0; kk < 8; ++kk) s[kk] = 0.f;
#pragma unroll
        for (int ct = 0; ct < 8; ++ct) {
          int col = ct * 16 + ln;
          float h1 = fmaxf(acc[grp][ct][r] + sBase[col], 0.f);
#pragma unroll
          for (int kk = 0; kk < 8; ++kk) s[kk] = fmaf(h1, sW2a[col * 9 + kk], s[kk]);
        }
#pragma unroll
        for (int off = 1; off < 16; off <<= 1)
#pragma unroll
          for (int kk = 0; kk < 8; ++kk) s[kk] += __shfl_xor(s[kk], off, 64);
        if (ln == 0) {
          float4 o0, o1;
          o0.x = s[0] + sB2[0]; o0.y = s[1] + sB2[1];
          o0.z = s[2] + sB2[2]; o0.w = s[3] + sB2[3];
          o1.x = s[4] + sB2[4]; o1.y = s[5] + sB2[5];
          o1.z = s[6] + sB2[6]; o1.w = s[7] + sB2[7];
          float4* dst = (float4*)(rawamps + (size_t)(b * NN + grow) * KK);
          dst[0] = o0; dst[1] = o1;
        }
      } else {
        float ps = 0.f;
#pragma unroll
        for (int ct = 0; ct < 8; ++ct) {
          int col = ct * 16 + ln;
          float hp = fmaxf(acc[grp][ct][r] + sBase[col], 0.f);
          ps = fmaf(hp, sP2[col], ps);
        }
#pragma unroll
        for (int off = 1; off < 16; off <<= 1) ps += __shfl_xor(ps, off, 64);
        if (ln == 0) pslogit[b * NN + grow] = ps + pb2v;
      }
    }
  }
}

// ---------------------------------------------------------------------------
// applyscale: amps = raw * (1 + sigmoid(psl) + label), re-laid-out to
// k-pair-major planes: ampsP[kp][gnode] as float2 (kp = 0..3).
// ---------------------------------------------------------------------------
__global__ __launch_bounds__(256) void applyscale(
    const float* __restrict__ raw, const float* __restrict__ psl,
    const int* __restrict__ lab, float* __restrict__ ampsP)
{
  int node = blockIdx.x * 256 + threadIdx.x;   // global node 0..131071
  float sc = 1.f + 1.f / (1.f + __expf(-psl[node])) + (float)lab[node];
  const float4* r = (const float4*)(raw + (size_t)node * KK);
  float4 v0 = r[0], v1 = r[1];
  float2* p = (float2*)ampsP;
  p[0 * (BB * NN) + node] = make_float2(v0.x * sc, v0.y * sc);
  p[1 * (BB * NN) + node] = make_float2(v0.z * sc, v0.w * sc);
  p[2 * (BB * NN) + node] = make_float2(v1.x * sc, v1.y * sc);
  p[3 * (BB * NN) + node] = make_float2(v1.z * sc, v1.w * sc);
}

// ---------------------------------------------------------------------------
// Diffusion step via LDS-resident plane. Block = (batch b, k-pair kp,
// replica rep of 8). Stage the 64 KB (8192 nodes x float2) plane coalesced,
// one barrier, then gather 16 neighbors per node from LDS (ds_read_b64).
// Per-step norms cancel; only final step computes the norm.
// ---------------------------------------------------------------------------
template<bool MUL, bool NRM>
__global__ __launch_bounds__(256) void sgl(
    const int* __restrict__ nbr, const float* __restrict__ src,
    const float* __restrict__ mult, float* __restrict__ out,
    float* __restrict__ normsq)
{
  __shared__ float2 sS[NN];                    // 64 KB
  const int g = blockIdx.x;
  const int kp = g & 3;
  const int rep = (g >> 2) & 7;
  const int b = g >> 5;
  const int t = threadIdx.x;

  const size_t pb = (size_t)kp * (BB * NN) + (size_t)b * NN;
  {
    const float4* p4 = (const float4*)((const float2*)src + pb);
    float4* s4 = (float4*)sS;
#pragma unroll
    for (int i = 0; i < 16; ++i) s4[t + i * 256] = p4[t + i * 256];
  }
  __syncthreads();

  const float2* mplane = (const float2*)mult + pb;
  float2* oplane = (float2*)out + pb;
  float ssacc = 0.f;
#pragma unroll
  for (int u = 0; u < 4; ++u) {
    int n = rep * 1024 + u * 256 + t;
    const int4* nbp = (const int4*)(nbr + ((size_t)b * NN + n) * DEG);
    int4 q0 = nbp[0], q1 = nbp[1], q2 = nbp[2], q3 = nbp[3];
    float ax = 0.f, ay = 0.f;
    float2 v;
    v = sS[q0.x]; ax += v.x; ay += v.y;
    v = sS[q0.y]; ax += v.x; ay += v.y;
    v = sS[q0.z]; ax += v.x; ay += v.y;
    v = sS[q0.w]; ax += v.x; ay += v.y;
    v = sS[q1.x]; ax += v.x; ay += v.y;
    v = sS[q1.y]; ax += v.x; ay += v.y;
    v = sS[q1.z]; ax += v.x; ay += v.y;
    v = sS[q1.w]; ax += v.x; ay += v.y;
    v = sS[q2.x]; ax += v.x; ay += v.y;
    v = sS[q2.y]; ax += v.x; ay += v.y;
    v = sS[q2.z]; ax += v.x; ay += v.y;
    v = sS[q2.w]; ax += v.x; ay += v.y;
    v = sS[q3.x]; ax += v.x; ay += v.y;
    v = sS[q3.y]; ax += v.x; ay += v.y;
    v = sS[q3.z]; ax += v.x; ay += v.y;
    v = sS[q3.w]; ax += v.x; ay += v.y;
    if (MUL) { float2 m = mplane[n]; ax *= m.x; ay *= m.y; }
    oplane[n] = make_float2(ax, ay);
    if (NRM) ssacc += ax * ax + ay * ay;
  }
  if (NRM) {
#pragma unroll
    for (int o = 1; o < 64; o <<= 1) ssacc += __shfl_xor(ssacc, o, 64);
    if ((t & 63) == 0) atomicAdd(&normsq[b], ssacc);
  }
}

__global__ __launch_bounds__(256) void fout(
    const float* __restrict__ u, const float* __restrict__ normsq,
    float* __restrict__ out)
{
  int node = blockIdx.x * 256 + threadIdx.x;   // global node
  float ns = normsq[node >> 13];
  float inv = ns > 0.f ? rsqrtf(ns) : 1.f;
  const float2* p = (const float2*)u;
  float2 v0 = p[0 * (BB * NN) + node];
  float2 v1 = p[1 * (BB * NN) + node];
  float2 v2 = p[2 * (BB * NN) + node];
  float2 v3 = p[3 * (BB * NN) + node];
  out[node] = (fabsf(v0.x) + fabsf(v0.y) + fabsf(v1.x) + fabsf(v1.y) +
               fabsf(v2.x) + fabsf(v2.y) + fabsf(v3.x) + fabsf(v3.y)) * inv;
}

extern "C" void kernel_launch(void* const* d_in, const int* in_sizes, int n_in,
                              void* d_out, int out_size, void* d_ws, size_t ws_size,
                              hipStream_t stream) {
  const float* q   = (const float*)d_in[0];
  const float* emb = (const float*)d_in[1];
  const int*   nbr = (const int*)d_in[2];
  const int*   lab = (const int*)d_in[3];
  const float* W1  = (const float*)d_in[4];
  const float* b1  = (const float*)d_in[5];
  const float* W2  = (const float*)d_in[6];
  const float* b2  = (const float*)d_in[7];
  const float* P1  = (const float*)d_in[8];
  const float* pb1 = (const float*)d_in[9];
  const float* P2  = (const float*)d_in[10];
  const float* pb2 = (const float*)d_in[11];
  float* out = (float*)d_out;

  const size_t NK = (size_t)BB * NN * KK;     // 1,048,576 floats (4 MB)
  float* ws     = (float*)d_ws;
  float* buf0   = ws;                         // raw amps (node-major), later u2m planes
  float* buf1   = buf0 + NK;                  // scaled-amp planes, later u3 planes
  float* buf2   = buf1 + NK;                  // u1m planes
  float* psl    = buf2 + NK;                  // 131072
  float* base1  = psl + (size_t)BB * NN;
  float* baseP  = base1 + BB * HH;
  float* normsq = baseP + BB * HH;
  unsigned short* W1t = (unsigned short*)(normsq + 16);
  unsigned short* P1t = W1t + (size_t)HH * DD;

  kprep<<<64, 256, 0, stream>>>(q, W1, b1, P1, pb1, W1t, P1t, base1, baseP, normsq);
  kgemm<<<1024, 512, 0, stream>>>(emb, W1t, P1t, base1, baseP, W2, b2, P2, pb2,
                                  buf0, psl);
  applyscale<<<512, 256, 0, stream>>>(buf0, psl, lab, buf1);
  sgl<true,  false><<<512, 256, 0, stream>>>(nbr, buf1, buf1, buf2, normsq); // u1m
  sgl<true,  false><<<512, 256, 0, stream>>>(nbr, buf2, buf1, buf0, normsq); // u2m
  sgl<false, true ><<<512, 256, 0, stream>>>(nbr, buf0, buf0, buf1, normsq); // u3 + norm
  fout<<<512, 256, 0, stream>>>(buf1, normsq, out);
}